// Round 1
// 476.306 us; speedup vs baseline: 1.0155x; 1.0155x over previous
//
#include <hip/hip_runtime.h>

// ---------------------------------------------------------------------------
// Attention_73813307949177
//   kx = k Wk^T + bk ; qx = q Wq^T + bq
//   score = softmax2(softmax1(qx kx^T + bias)*wei + bias)
//   out = score (kx Wp^T) + bp   [associativity, validated R9]
// Outputs (concat): out [4096,1024] fp32, score [4096,4096] fp32
//
// R10 -> R11: SCHEDULE. gemm_score_kxp was the m97-class 2-barrier
// single-buffered loop (measured MfmaUtil 40%, 121us vs ~45us MFMA floor).
// Replaced by gemm_score256: 256x256 tile, 512 thr (8 waves 2Mx4N),
// double-buffered 128KB LDS, 4 phases per K-tile with counted vmcnt
// (loads in flight across raw s_barriers), setprio(1) around MFMA
// clusters. Accumulation order bit-identical to R10. kxpT (one 128x128
// tile per block) folded in after the score epilogue.
// ---------------------------------------------------------------------------

typedef __bf16 bf16;
typedef __bf16 bf16x8 __attribute__((ext_vector_type(8)));
typedef __bf16 bf16x4 __attribute__((ext_vector_type(4)));
typedef float  f32x4  __attribute__((ext_vector_type(4)));
typedef float  f32x16 __attribute__((ext_vector_type(16)));
typedef int    i32x4  __attribute__((ext_vector_type(4)));

typedef __attribute__((address_space(1))) void as1_void;
typedef __attribute__((address_space(3))) void as3_void;

#define NQ  4096
#define NKK 4096
#define EMB 1024

#define BM 128
#define BN 128
#define BK 32

__device__ __forceinline__ void gld_lds16(const void* g, void* l) {
    __builtin_amdgcn_global_load_lds((as1_void*)g, (as3_void*)l, 16, 0, 0);
}

// ---------------------------------------------------------------------------
// prep: fp32 -> bf16 hi/lo split; 5 tensors batched via blockIdx.y
__global__ __launch_bounds__(256) void prep_all(
    const float* __restrict__ q, const float* __restrict__ k,
    const float* __restrict__ Wq, const float* __restrict__ Wk, const float* __restrict__ Wp,
    bf16* __restrict__ qh, bf16* __restrict__ ql,
    bf16* __restrict__ kh, bf16* __restrict__ kl,
    bf16* __restrict__ Wqh, bf16* __restrict__ Wql,
    bf16* __restrict__ Wkh, bf16* __restrict__ Wkl,
    bf16* __restrict__ Wph, bf16* __restrict__ Wpl,
    int nqk, int nw)
{
    const int z = blockIdx.y;
    const float* s; bf16* h; bf16* l; int n;
    switch (z) {
        case 0:  s = q;  h = qh;  l = ql;  n = nqk; break;
        case 1:  s = k;  h = kh;  l = kl;  n = nqk; break;
        case 2:  s = Wq; h = Wqh; l = Wql; n = nw;  break;
        case 3:  s = Wk; h = Wkh; l = Wkl; n = nw;  break;
        default: s = Wp; h = Wph; l = Wpl; n = nw;  break;
    }
    const int i = (blockIdx.x * 256 + threadIdx.x) * 4;
    if (i >= n) return;
    f32x4 v = *(const f32x4*)(s + i);
    bf16x4 hv, lv;
#pragma unroll
    for (int c = 0; c < 4; c++) {
        float x = v[c];
        bf16 hh = (bf16)x;
        hv[c] = hh;
        lv[c] = (bf16)(x - (float)hh);
    }
    *(bf16x4*)(h + i) = hv;
    *(bf16x4*)(l + i) = lv;
}

// ---------------------------------------------------------------------------
// reduce over NS partial slices. MODE 0: sum->bf16. MODE 1: sum+bias->f32.
template<int NS, int MODE>
__global__ __launch_bounds__(256) void reduce_k(
    const float* __restrict__ P, const float* __restrict__ bias,
    float* __restrict__ of, bf16* __restrict__ oh, int n, int Nld)
{
    const int i = (blockIdx.x * 256 + threadIdx.x) * 4;
    if (i >= n) return;
    f32x4 v = *(const f32x4*)(P + i);
#pragma unroll
    for (int s = 1; s < NS; s++)
        v += *(const f32x4*)(P + (size_t)s * n + i);
    if (MODE == 1)
        v += *(const f32x4*)(bias + (i & (Nld - 1)));
    if (MODE == 0) {
        bf16x4 o;
#pragma unroll
        for (int c = 0; c < 4; c++) o[c] = (bf16)v[c];
        *(bf16x4*)(oh + i) = o;
    } else {
        *(f32x4*)(of + i) = v;
    }
}

// ---------------------------------------------------------------------------
// Plain bf16 gemm_bt (32x32x16 core, swizzled LDS): C = A[M,K] B[N,K]^T.
// NSPLIT>0: blockIdx.z = kz -> fp32 partial slice kz.
template<int NSPLIT, int HAS_BIAS, int OUT_BF16>
__global__ __launch_bounds__(256) void gemm_bt(
    const bf16* __restrict__ A, const bf16* __restrict__ B,
    const float* __restrict__ bias,
    float* __restrict__ Cf, bf16* __restrict__ Cb,
    int M, int N, int Ksub, int lda, int ldb)
{
    __shared__ bf16 sA[BM * BK];
    __shared__ bf16 sB[BN * BK];
    const int t    = threadIdx.x;
    const int wave = t >> 6;
    const int lane = t & 63;
    const int l31  = lane & 31;
    const int lhi  = lane >> 5;
    const int wm   = wave >> 1;
    const int wn   = wave & 1;
    const int bm   = blockIdx.y * BM;
    const int bn   = blockIdx.x * BN;
    const int srow = t >> 2;
    const int gseg = (t & 3) ^ ((srow >> 1) & 3);
    const int rsw  = (l31 >> 1) & 3;
    const int kz   = (NSPLIT > 0) ? (int)blockIdx.z : 0;

    A += (size_t)kz * Ksub;
    B += (size_t)kz * Ksub;
    if (NSPLIT > 0) Cf += (size_t)kz * M * N;

    const bf16* ga = A + (size_t)(bm + srow) * lda + gseg * 8;
    const bf16* gb = B + (size_t)(bn + srow) * ldb + gseg * 8;
    char* lA = (char*)sA + wave * 1024;
    char* lB = (char*)sB + wave * 1024;

    f32x16 acc[2][2] = {};

    for (int k0 = 0; k0 < Ksub; k0 += BK) {
        __syncthreads();
        gld_lds16(ga + k0,                      lA);
        gld_lds16(ga + (size_t)64 * lda + k0,   lA + 4096);
        gld_lds16(gb + k0,                      lB);
        gld_lds16(gb + (size_t)64 * ldb + k0,   lB + 4096);
        __syncthreads();
        bf16x8 af[2][2], bfr[2][2];
#pragma unroll
        for (int mi = 0; mi < 2; mi++)
#pragma unroll
            for (int kh = 0; kh < 2; kh++)
                af[mi][kh] = *(const bf16x8*)
                    &sA[(wm * 64 + mi * 32 + l31) * BK + ((kh * 2 + lhi) ^ rsw) * 8];
#pragma unroll
        for (int nj = 0; nj < 2; nj++)
#pragma unroll
            for (int kh = 0; kh < 2; kh++)
                bfr[nj][kh] = *(const bf16x8*)
                    &sB[(wn * 64 + nj * 32 + l31) * BK + ((kh * 2 + lhi) ^ rsw) * 8];
#pragma unroll
        for (int kh = 0; kh < 2; kh++)
#pragma unroll
            for (int mi = 0; mi < 2; mi++)
#pragma unroll
                for (int nj = 0; nj < 2; nj++)
                    acc[mi][nj] = __builtin_amdgcn_mfma_f32_32x32x16_bf16(
                        af[mi][kh], bfr[nj][kh], acc[mi][nj], 0, 0, 0);
    }

#pragma unroll
    for (int mi = 0; mi < 2; mi++)
#pragma unroll
        for (int nj = 0; nj < 2; nj++) {
            const int cg = bn + wn * 64 + nj * 32 + l31;
            const float bv = HAS_BIAS ? bias[cg] : 0.0f;
#pragma unroll
            for (int r = 0; r < 16; r++) {
                const int rg = bm + wm * 64 + mi * 32 + (r & 3) + 8 * (r >> 2) + 4 * lhi;
                const float v = acc[mi][nj][r] + bv;
                const size_t idx = (size_t)rg * N + cg;
                if (NSPLIT > 0)    Cf[idx] = v;
                else if (OUT_BF16) Cb[idx] = (bf16)v;
                else               Cf[idx] = v;
            }
        }
}

// ---------------------------------------------------------------------------
// Split-precision gemm_bt (32x32x16, 2x2 wave tile; AlBh + AhBl + AhBh).
// Projections: BATCH via blockIdx.z, direct bias + hi/lo epilogue.
template<int BATCH, int HAS_BIAS, int HILO>
__global__ __launch_bounds__(256) void gemm_bt_split(
    const bf16* __restrict__ Ah0, const bf16* __restrict__ Al0,
    const bf16* __restrict__ Bh0, const bf16* __restrict__ Bl0,
    const float* __restrict__ bias0, bf16* __restrict__ Ch0, bf16* __restrict__ Cl0,
    const bf16* __restrict__ Ah1, const bf16* __restrict__ Al1,
    const bf16* __restrict__ Bh1, const bf16* __restrict__ Bl1,
    const float* __restrict__ bias1, bf16* __restrict__ Ch1, bf16* __restrict__ Cl1,
    float* __restrict__ Cf,
    int M, int N, int K)
{
    __shared__ bf16 sAh[BM * BK], sAl[BM * BK], sBh[BN * BK], sBl[BN * BK];
    const int t    = threadIdx.x;
    const int wave = t >> 6;
    const int lane = t & 63;
    const int l31  = lane & 31;
    const int lhi  = lane >> 5;
    const int wm   = wave >> 1;
    const int wn   = wave & 1;
    const int bm   = blockIdx.y * BM;
    const int bn   = blockIdx.x * BN;
    const int srow = t >> 2;
    const int gseg = (t & 3) ^ ((srow >> 1) & 3);
    const int rsw  = (l31 >> 1) & 3;

    const int mt = BATCH ? (int)blockIdx.z : 0;

    const bf16* Ah = (BATCH && mt) ? Ah1 : Ah0;
    const bf16* Al = (BATCH && mt) ? Al1 : Al0;
    const bf16* Bh = (BATCH && mt) ? Bh1 : Bh0;
    const bf16* Bl = (BATCH && mt) ? Bl1 : Bl0;
    const float* bias = (BATCH && mt) ? bias1 : bias0;
    bf16* Ch = (BATCH && mt) ? Ch1 : Ch0;
    bf16* Cl = (BATCH && mt) ? Cl1 : Cl0;

    const size_t offA = (size_t)(bm + srow) * K + gseg * 8;
    const size_t offB = (size_t)(bn + srow) * K + gseg * 8;
    char* lAh = (char*)sAh + wave * 1024;
    char* lAl = (char*)sAl + wave * 1024;
    char* lBh = (char*)sBh + wave * 1024;
    char* lBl = (char*)sBl + wave * 1024;

    f32x16 acc[2][2] = {};

    for (int k0 = 0; k0 < K; k0 += BK) {
        __syncthreads();
        gld_lds16(Ah + offA + k0,                  lAh);
        gld_lds16(Ah + offA + (size_t)64 * K + k0, lAh + 4096);
        gld_lds16(Al + offA + k0,                  lAl);
        gld_lds16(Al + offA + (size_t)64 * K + k0, lAl + 4096);
        gld_lds16(Bh + offB + k0,                  lBh);
        gld_lds16(Bh + offB + (size_t)64 * K + k0, lBh + 4096);
        gld_lds16(Bl + offB + k0,                  lBl);
        gld_lds16(Bl + offB + (size_t)64 * K + k0, lBl + 4096);
        __syncthreads();
#pragma unroll
        for (int kh = 0; kh < 2; kh++) {
            const int ksw = ((kh * 2 + lhi) ^ rsw) * 8;
            bf16x8 ah[2], al[2], bh2[2], bl2[2];
#pragma unroll
            for (int mi = 0; mi < 2; mi++) {
                const int ro = (wm * 64 + mi * 32 + l31) * BK + ksw;
                ah[mi] = *(const bf16x8*)&sAh[ro];
                al[mi] = *(const bf16x8*)&sAl[ro];
            }
#pragma unroll
            for (int nj = 0; nj < 2; nj++) {
                const int ro = (wn * 64 + nj * 32 + l31) * BK + ksw;
                bh2[nj] = *(const bf16x8*)&sBh[ro];
                bl2[nj] = *(const bf16x8*)&sBl[ro];
            }
#pragma unroll
            for (int mi = 0; mi < 2; mi++)
#pragma unroll
                for (int nj = 0; nj < 2; nj++) {
                    acc[mi][nj] = __builtin_amdgcn_mfma_f32_32x32x16_bf16(al[mi], bh2[nj], acc[mi][nj], 0, 0, 0);
                    acc[mi][nj] = __builtin_amdgcn_mfma_f32_32x32x16_bf16(ah[mi], bl2[nj], acc[mi][nj], 0, 0, 0);
                    acc[mi][nj] = __builtin_amdgcn_mfma_f32_32x32x16_bf16(ah[mi], bh2[nj], acc[mi][nj], 0, 0, 0);
                }
        }
    }

#pragma unroll
    for (int mi = 0; mi < 2; mi++)
#pragma unroll
        for (int nj = 0; nj < 2; nj++) {
            const int cg = bn + wn * 64 + nj * 32 + l31;
            const float bv = HAS_BIAS ? bias[cg] : 0.0f;
#pragma unroll
            for (int r = 0; r < 16; r++) {
                const int rg = bm + wm * 64 + mi * 32 + (r & 3) + 8 * (r >> 2) + 4 * lhi;
                const float v = acc[mi][nj][r] + bv;
                const size_t idx = (size_t)rg * N + cg;
                if (HILO) {
                    const bf16 hh = (bf16)v;
                    Ch[idx] = hh;
                    Cl[idx] = (bf16)(v - (float)hh);
                } else {
                    Cf[idx] = v;
                }
            }
        }
}

// ---------------------------------------------------------------------------
// R11 score GEMM: logits = qx kx^T (split precision), 256x256 tile,
// 512 threads = 8 waves (2M x 4N, per-wave 128x64 -> acc[4][2]).
// Double-buffered 128KB LDS, 4 phases per K-tile (BK=32):
//   ph = {kh half x mi pair}; each phase: ds_read subtile (+B frags on
//   even phases) -> prefetch gld_lds for tile t+1 (A pair ph0, B pair ph1)
//   -> s_barrier -> lgkmcnt(0)+sched_barrier -> setprio(1) 12 MFMA
//   setprio(0) -> (ph3: vmcnt(0)) -> s_barrier.
// Loads stay in flight across barriers (no __syncthreads drain).
// Accumulation order per output element identical to R10 (bit-exact).
// After the score epilogue each block computes one 128x128 tile of
// kxpT = Wp kx^T (plain bf16, small counted-vmcnt dbuf loop).
__global__ __launch_bounds__(512, 2) void gemm_score256(
    const bf16* __restrict__ Ah, const bf16* __restrict__ Al,
    const bf16* __restrict__ Bh, const bf16* __restrict__ Bl,
    float* __restrict__ Cf,
    const bf16* __restrict__ Wp, const bf16* __restrict__ Kx,
    bf16* __restrict__ kxpT)
{
    __shared__ bf16 smem[65536];          // 128 KB: 2 x {Ah,Al,Bh,Bl} x 256x32
    const int t    = threadIdx.x;
    const int wave = t >> 6;              // 0..7
    const int lane = t & 63;
    const int l31  = lane & 31;
    const int lhi  = lane >> 5;
    const int wm   = wave >> 2;           // 0..1 (M)
    const int wn   = wave & 3;            // 0..3 (N)
    const int bm   = (blockIdx.x >> 4) * 256;
    const int bn   = (blockIdx.x & 15) * 256;
    const int srow = t >> 2;              // 0..127
    const int gseg = (t & 3) ^ ((srow >> 1) & 3);
    const int rsw  = (l31 >> 1) & 3;
    const int K    = EMB;
    const int NT   = K / BK;              // 32 K-tiles

    const bf16* gAh = Ah + (size_t)(bm + srow) * K + gseg * 8;
    const bf16* gAl = Al + (size_t)(bm + srow) * K + gseg * 8;
    const bf16* gBh = Bh + (size_t)(bn + srow) * K + gseg * 8;
    const bf16* gBl = Bl + (size_t)(bn + srow) * K + gseg * 8;

    // buffer b (bytes): Ah @ b*65536+0, Al @ +16384, Bh @ +32768, Bl @ +49152
    auto stageA = [&](int buf, int k0) {
        char* L = (char*)smem + buf * 65536 + wave * 1024;
        gld_lds16(gAh + k0,                   L + 0);
        gld_lds16(gAh + (size_t)128 * K + k0, L + 8192);
        gld_lds16(gAl + k0,                   L + 16384);
        gld_lds16(gAl + (size_t)128 * K + k0, L + 16384 + 8192);
    };
    auto stageB = [&](int buf, int k0) {
        char* L = (char*)smem + buf * 65536 + wave * 1024;
        gld_lds16(gBh + k0,                   L + 32768);
        gld_lds16(gBh + (size_t)128 * K + k0, L + 32768 + 8192);
        gld_lds16(gBl + k0,                   L + 49152);
        gld_lds16(gBl + (size_t)128 * K + k0, L + 49152 + 8192);
    };

    f32x16 acc[4][2] = {};

    stageA(0, 0);
    stageB(0, 0);
    asm volatile("s_waitcnt vmcnt(0)" ::: "memory");
    __builtin_amdgcn_s_barrier();

    for (int tt = 0; tt < NT; ++tt) {
        const int cur = tt & 1;
        const int cb  = cur * 32768;      // elem base of current buffer
        const int kn  = (tt + 1) * BK;
        bf16x8 bh2[2], bl2[2];
#pragma unroll
        for (int ph = 0; ph < 4; ++ph) {
            const int kh   = ph >> 1;
            const int half = ph & 1;
            const int ksw  = ((kh * 2 + lhi) ^ rsw) * 8;
            if (half == 0) {
#pragma unroll
                for (int nj = 0; nj < 2; nj++) {
                    const int ro = cb + 16384 + (wn * 64 + nj * 32 + l31) * BK + ksw;
                    bh2[nj] = *(const bf16x8*)&smem[ro];
                    bl2[nj] = *(const bf16x8*)&smem[ro + 8192];
                }
            }
            bf16x8 a_h[2], a_l[2];
#pragma unroll
            for (int i = 0; i < 2; i++) {
                const int ro = cb + (wm * 128 + (half * 2 + i) * 32 + l31) * BK + ksw;
                a_h[i] = *(const bf16x8*)&smem[ro];
                a_l[i] = *(const bf16x8*)&smem[ro + 8192];
            }
            if (tt < NT - 1) {
                if (ph == 0)      stageA(cur ^ 1, kn);
                else if (ph == 1) stageB(cur ^ 1, kn);
            }
            __builtin_amdgcn_s_barrier();
            asm volatile("s_waitcnt lgkmcnt(0)" ::: "memory");
            __builtin_amdgcn_sched_barrier(0);
            __builtin_amdgcn_s_setprio(1);
#pragma unroll
            for (int i = 0; i < 2; i++) {
                const int mi = half * 2 + i;
#pragma unroll
                for (int nj = 0; nj < 2; nj++) {
                    acc[mi][nj] = __builtin_amdgcn_mfma_f32_32x32x16_bf16(a_l[i], bh2[nj], acc[mi][nj], 0, 0, 0);
                    acc[mi][nj] = __builtin_amdgcn_mfma_f32_32x32x16_bf16(a_h[i], bl2[nj], acc[mi][nj], 0, 0, 0);
                    acc[mi][nj] = __builtin_amdgcn_mfma_f32_32x32x16_bf16(a_h[i], bh2[nj], acc[mi][nj], 0, 0, 0);
                }
            }
            __builtin_amdgcn_s_setprio(0);
            if (ph == 3)
                asm volatile("s_waitcnt vmcnt(0)" ::: "memory");
            __builtin_amdgcn_s_barrier();
        }
    }

    // ---- score C-write (fp32 logits)
#pragma unroll
    for (int mi = 0; mi < 4; mi++)
#pragma unroll
        for (int nj = 0; nj < 2; nj++) {
            const int cg = bn + wn * 64 + nj * 32 + l31;
#pragma unroll
            for (int r = 0; r < 16; r++) {
                const int rg = bm + wm * 128 + mi * 32 + (r & 3) + 8 * (r >> 2) + 4 * lhi;
                Cf[(size_t)rg * NKK + cg] = acc[mi][nj][r];
            }
        }

    // ---- kxpT tile: C[m,n] = sum_k Wp[m,k] Kx[n,k]; 128x128 per block.
    // 8 waves (4M x 2N, per-wave 32x64). LDS reuse of first 32 KB is safe:
    // all score-loop LDS reads were consumed before the final barrier.
    {
        const int km  = (blockIdx.x >> 5) * 128;   // over EMB/128 = 8
        const int kn2 = (blockIdx.x & 31) * 128;   // over NKK/128 = 32
        const int wm4 = wave >> 1;
        const int wn2 = wave & 1;
        const bf16* gW = Wp + (size_t)(km  + srow) * K + gseg * 8;
        const bf16* gX = Kx + (size_t)(kn2 + srow) * K + gseg * 8;
        // buffer b (bytes): W @ b*16384+0, X @ +8192
        auto stageK = [&](int buf, int k0) {
            char* L = (char*)smem + buf * 16384 + wave * 1024;
            gld_lds16(gW + k0, L);
            gld_lds16(gX + k0, L + 8192);
        };
        f32x16 ac2[2] = {};
        stageK(0, 0);
        for (int it = 0; it < NT; ++it) {
            const int cur = it & 1;
            const int cb  = cur * 8192;    // elem base
            if (it < NT - 1) {
                stageK(cur ^ 1, (it + 1) * BK);
                asm volatile("s_waitcnt vmcnt(2)" ::: "memory");
            } else {
                asm volatile("s_waitcnt vmcnt(0)" ::: "memory");
            }
            __builtin_amdgcn_s_barrier();
#pragma unroll
            for (int kh = 0; kh < 2; kh++) {
                const int ksw = ((kh * 2 + lhi) ^ rsw) * 8;
                bf16x8 av  = *(const bf16x8*)&smem[cb + (wm4 * 32 + l31) * BK + ksw];
                bf16x8 bv0 = *(const bf16x8*)&smem[cb + 4096 + (wn2 * 64 + l31) * BK + ksw];
                bf16x8 bv1 = *(const bf16x8*)&smem[cb + 4096 + (wn2 * 64 + 32 + l31) * BK + ksw];
                ac2[0] = __builtin_amdgcn_mfma_f32_32x32x16_bf16(av, bv0, ac2[0], 0, 0, 0);
                ac2[1] = __builtin_amdgcn_mfma_f32_32x32x16_bf16(av, bv1, ac2[1], 0, 0, 0);
            }
            asm volatile("s_waitcnt lgkmcnt(0)" ::: "memory");
            __builtin_amdgcn_s_barrier();
        }
#pragma unroll
        for (int nj = 0; nj < 2; nj++) {
            const int cg = kn2 + wn2 * 64 + nj * 32 + l31;
#pragma unroll
            for (int r = 0; r < 16; r++) {
                const int rg = km + wm4 * 32 + (r & 3) + 8 * (r >> 2) + 4 * lhi;
                kxpT[(size_t)rg * NKK + cg] = (bf16)ac2[nj][r];
            }
        }
    }
}

// ---------------------------------------------------------------------------
__device__ __forceinline__ float wred_max(float v) {
#pragma unroll
    for (int off = 32; off > 0; off >>= 1) v = fmaxf(v, __shfl_xor(v, off));
    return v;
}
__device__ __forceinline__ float wred_sum(float v) {
#pragma unroll
    for (int off = 32; off > 0; off >>= 1) v += __shfl_xor(v, off);
    return v;
}

// Fused double softmax, vectorized (16 contiguous cols/thread).
__global__ __launch_bounds__(256) void softmax2_kernel(
    float* __restrict__ score, const int* __restrict__ mask,
    const float* __restrict__ wei, bf16* __restrict__ scoreb)
{
    __shared__ float sred[4];
    const int row = blockIdx.x;
    const int t   = threadIdx.x;
    const size_t base = (size_t)row * NKK + (size_t)t * 16;
    const int wv = t >> 6, ln = t & 63;

    float l[16], w[16];
    unsigned mb = 0;
#pragma unroll
    for (int c = 0; c < 4; c++) {
        *(f32x4*)(l + 4 * c) = *(const f32x4*)(score + base + 4 * c);
        *(f32x4*)(w + 4 * c) = *(const f32x4*)(wei + base + 4 * c);
        i32x4 mv = *(const i32x4*)(mask + base + 4 * c);
#pragma unroll
        for (int j = 0; j < 4; j++) if (mv[j] != 0) mb |= 1u << (4 * c + j);
    }

    // pass 1
    float mx = -__builtin_inff();
#pragma unroll
    for (int s = 0; s < 16; s++) if (mb & (1u << s)) mx = fmaxf(mx, l[s]);
    mx = wred_max(mx);
    if (ln == 0) sred[wv] = mx;
    __syncthreads();
    mx = fmaxf(fmaxf(sred[0], sred[1]), fmaxf(sred[2], sred[3]));
    __syncthreads();
    float sum = 0.f;
#pragma unroll
    for (int s = 0; s < 16; s++) {
        const float e = (mb & (1u << s)) ? __expf(l[s] - mx) : 0.f;
        l[s] = e; sum += e;
    }
    sum = wred_sum(sum);
    if (ln == 0) sred[wv] = sum;
    __syncthreads();
    sum = sred[0] + sred[1] + sred[2] + sred[3];
    __syncthreads();
    const float inv1 = 1.0f / sum;

#pragma unroll
    for (int s = 0; s < 16; s++) l[s] = l[s] * inv1 * w[s];

    // pass 2
    float mx2 = -__builtin_inff();
#pragma unroll
    for (int s = 0; s < 16; s++) if (mb & (1u << s)) mx2 = fmaxf(mx2, l[s]);
    mx2 = wred_max(mx2);
    if (ln == 0) sred[wv] = mx2;
    __syncthreads();
    mx2 = fmaxf(fmaxf(sred[0], sred[1]), fmaxf(sred[2], sred[3]));
    __syncthreads();
    float sum2 = 0.f;
#pragma unroll
    for (int s = 0; s < 16; s++) {
        const float e = (mb & (1u << s)) ? __expf(l[s] - mx2) : 0.f;
        l[s] = e; sum2 += e;
    }
    sum2 = wred_sum(sum2);
    if (ln == 0) sred[wv] = sum2;
    __syncthreads();
    sum2 = sred[0] + sred[1] + sred[2] + sred[3];
    const float inv2 = 1.0f / sum2;

#pragma unroll
    for (int c = 0; c < 4; c++) {
        f32x4 pv;
#pragma unroll
        for (int j = 0; j < 4; j++) pv[j] = l[4 * c + j] * inv2;
        __builtin_nontemporal_store(pv, (f32x4*)(score + base + 4 * c));
#pragma unroll
        for (int j = 0; j < 4; j++) l[4 * c + j] = pv[j];
    }
    bf16x8 b0, b1;
#pragma unroll
    for (int j = 0; j < 8; j++) { b0[j] = (bf16)l[j]; b1[j] = (bf16)l[8 + j]; }
    *(bf16x8*)(scoreb + base)     = b0;
    *(bf16x8*)(scoreb + base + 8) = b1;
}

// ---------------------------------------------------------------------------
extern "C" void kernel_launch(void* const* d_in, const int* in_sizes, int n_in,
                              void* d_out, int out_size, void* d_ws, size_t ws_size,
                              hipStream_t stream)
{
    (void)in_sizes; (void)n_in; (void)out_size;
    const float* q    = (const float*)d_in[0];
    const float* k    = (const float*)d_in[1];
    const int*   mask = (const int*)  d_in[2];
    const float* wei  = (const float*)d_in[3];
    const float* Wq   = (const float*)d_in[4];
    const float* bq   = (const float*)d_in[5];
    const float* Wk   = (const float*)d_in[6];
    const float* bk   = (const float*)d_in[7];
    const float* Wp   = (const float*)d_in[8];
    const float* bp   = (const float*)d_in[9];

    float* out   = (float*)d_out;
    float* score = (float*)d_out + (size_t)NQ * EMB;

    char* ws = (char*)d_ws;
    size_t off = 0;
    auto alloc = [&](size_t bytes) -> char* {
        char* p = ws + off; off += (bytes + 255) & ~(size_t)255; return p;
    };
    const size_t n_qk = (size_t)NQ * EMB;
    const size_t n_w  = (size_t)EMB * EMB;
    const size_t n_sc = (size_t)NQ * NKK;

    bf16* qh   = (bf16*)alloc(n_qk * 2);
    bf16* ql   = (bf16*)alloc(n_qk * 2);
    bf16* kh   = (bf16*)alloc(n_qk * 2);
    bf16* kl   = (bf16*)alloc(n_qk * 2);
    bf16* qxh  = (bf16*)alloc(n_qk * 2);
    bf16* qxl  = (bf16*)alloc(n_qk * 2);
    bf16* kxh  = (bf16*)alloc(n_qk * 2);
    bf16* kxl  = (bf16*)alloc(n_qk * 2);
    bf16* Wqh  = (bf16*)alloc(n_w * 2);
    bf16* Wql  = (bf16*)alloc(n_w * 2);
    bf16* Wkh  = (bf16*)alloc(n_w * 2);
    bf16* Wkl  = (bf16*)alloc(n_w * 2);
    bf16* Wpb  = (bf16*)alloc(n_w * 2);
    bf16* Wpl  = (bf16*)alloc(n_w * 2);
    bf16* kxpTb = (bf16*)alloc(n_qk * 2);   // kxpT = Wp kx^T  [1024 x 4096]
    bf16* scoreb = (bf16*)alloc(n_sc * 2);
    const size_t base_off = off;
    float* P = (float*)alloc(2 * n_qk * 4); // 33.5 MB partials (split-K=2)
    const bool ws_ok = (off <= ws_size);
    if (base_off > ws_size) return;

    const int MN = (int)n_qk;

    // 1) prep: all 5 hi/lo splits in one launch
    prep_all<<<dim3(n_qk / 1024, 5), 256, 0, stream>>>(
        q, k, Wq, Wk, Wp,
        qh, ql, kh, kl, Wqh, Wql, Wkh, Wkl, Wpb, Wpl,
        (int)n_qk, (int)n_w);

    // 2) projections: batched z=2, direct bias + hi/lo epilogue
    gemm_bt_split<1, 1, 1><<<dim3(EMB / BN, NQ / BM, 2), 256, 0, stream>>>(
        qh, ql, Wqh, Wql, bq, qxh, qxl,
        kh, kl, Wkh, Wkl, bk, kxh, kxl,
        nullptr, NQ, EMB, EMB);

    // 3) score logits (256 blocks, 256x256 tile, 4-phase pipelined) with
    //    one 128x128 kxpT = Wp kx^T tile per block appended
    gemm_score256<<<dim3(256), 512, 0, stream>>>(
        qxh, qxl, kxh, kxl, score, Wpb, kxh, kxpTb);

    // 4) fused double softmax (vectorized, mask int4, p2 nontemporal)
    softmax2_kernel<<<dim3(NQ), 256, 0, stream>>>(score, mask, wei, scoreb);

    // 5) out = p2 kxp + bp  (split-K=2 over K=4096)
    if (ws_ok) {
        gemm_bt<2, 0, 0><<<dim3(EMB / BN, NQ / BM, 2), 256, 0, stream>>>(
            scoreb, kxpTb, nullptr, P, nullptr, NQ, EMB, NKK / 2, NKK, NKK);
        reduce_k<2, 1><<<dim3(MN / 1024), 256, 0, stream>>>(
            P, bp, out, nullptr, MN, EMB);
    } else {
        gemm_bt<0, 1, 0><<<dim3(EMB / BN, NQ / BM), 256, 0, stream>>>(
            scoreb, kxpTb, bp, out, nullptr, NQ, EMB, NKK, NKK, NKK);
    }
}